// Round 9
// baseline (116.526 us; speedup 1.0000x reference)
//
#include <hip/hip_runtime.h>
#include <math.h>

#define HID 128
#define CIN 64
#define NB 8
#define HD 128
#define WD 128
#define HW (HD*WD)   // 16384

typedef float v2f __attribute__((ext_vector_type(2)));
typedef _Float16 h2 __attribute__((ext_vector_type(2)));
typedef _Float16 h4 __attribute__((ext_vector_type(4)));

// wcomp layout (floats, after the three fp16 fields in ws):
//   [0, 24576)      wg[og=8][c=64][48] : {W_in row | Wd' row | Wb' row} for 16 outs
//   [24576, 24704)  bd'[128]
//   [24704, 24832)  bb'[128]
#define WG_OFF 0
#define BD_OFF 24576
#define BB_OFF 24704

// ======= L0: weight compose, ONCE (was recomputed per gate block = 128x redundant) =======
__global__ __launch_bounds__(256) void wprep_kernel(const float* __restrict__ W_in,
                                                    const float* __restrict__ b_in,
                                                    const float* __restrict__ W_delta,
                                                    const float* __restrict__ b_delta,
                                                    const float* __restrict__ W_B,
                                                    const float* __restrict__ b_B,
                                                    float* __restrict__ wcomp) {
    int bid = blockIdx.x, tid = threadIdx.x;
    if (bid < 32) {
        int idx = bid * 256 + tid;                         // [0,8192) = HID*CIN
        int o = idx >> 6, c = idx & 63;
        float wd = 0.f, wb = 0.f;
        for (int h = 0; h < HID; ++h) {
            float wi = W_in[h * CIN + c];
            wd = fmaf(W_delta[o * HID + h], wi, wd);
            wb = fmaf(W_B[o * HID + h], wi, wb);
        }
        int og = o >> 4, j = o & 15;
        float* base = wcomp + WG_OFF + og * (CIN * 48) + c * 48;
        base[j]      = W_in[o * CIN + c];
        base[16 + j] = wd;
        base[32 + j] = wb;
        return;
    }
    if (tid < HID) {
        float sd = b_delta[tid], sb = b_B[tid];
        for (int h = 0; h < HID; ++h) {
            float bi = b_in[h];
            sd = fmaf(W_delta[tid * HID + h], bi, sd);
            sb = fmaf(W_B[tid * HID + h], bi, sb);
        }
        wcomp[BD_OFF + tid] = sd;
        wcomp[BB_OFF + tid] = sb;
    }
}

// ======= L1: fused gate (round-6 winner, compose replaced by cheap LDS stage) =======
__global__ __launch_bounds__(256, 2) void gate_kernel(const float* __restrict__ x,
                                                      const float* __restrict__ prior,
                                                      const float* __restrict__ b_in,
                                                      const float* __restrict__ wcomp,
                                                      const float* __restrict__ lam_p,
                                                      const float* __restrict__ alpha_p,
                                                      const float* __restrict__ A,
                                                      const float* __restrict__ gamma_p,
                                                      _Float16* __restrict__ Abar,
                                                      _Float16* __restrict__ bbuf,
                                                      float* __restrict__ out0,
                                                      float* __restrict__ out1) {
    __shared__ float swf[CIN * 48];                        // {W_in | Wd' | Wb'} x 16 outs, 12 KB
    __shared__ float sbd[16], sbb[16], snA[16], sbi[16];
    const int bx = blockIdx.x, og = blockIdx.y, b = blockIdx.z;
    const int tid = threadIdx.x;
    const int p0 = bx * 1024 + tid * 4;
    const float g = gamma_p[0];

    // ---- inline prior upsample for this thread's 4 px (same row) ----
    const float scale = 63.0f / 127.0f;
    int i = p0 >> 7;
    float ys = i * scale;
    int y0 = (int)floorf(ys); int y1 = min(y0 + 1, 63);
    float wy = ys - (float)y0;
    const float* pp = prior + b * 4096;
    int col0 = p0 & 127;
    float pus[4];
#pragma unroll
    for (int k = 0; k < 4; ++k) {
        float xs = (col0 + k) * scale;
        int x0 = (int)floorf(xs); int x1 = min(x0 + 1, 63);
        float wx = xs - (float)x0;
        float v00 = pp[y0 * 64 + x0], v01 = pp[y0 * 64 + x1];
        float v10 = pp[y1 * 64 + x0], v11 = pp[y1 * 64 + x1];
        float r0 = v00 * (1.f - wy) + v10 * wy;
        float r1 = v01 * (1.f - wy) + v11 * wy;
        float v = r0 * (1.f - wx) + r1 * wx;
        pus[k] = fminf(fmaxf(v, -1.f), 1.f);
    }
    if (og == 0)
        *(float4*)(out1 + b * HW + p0) = make_float4(pus[0], pus[1], pus[2], pus[3]);

    // ---- gamma==0: out0 = x (this block's 8-channel slab), done ----
    if (g == 0.f) {
        const float* xs0 = x + b * (CIN * HW) + (og * 8) * HW + p0;
        float* o0 = out0 + b * (CIN * HW) + (og * 8) * HW + p0;
#pragma unroll
        for (int ch = 0; ch < 8; ++ch)
            *(float4*)(o0 + ch * HW) = *(const float4*)(xs0 + ch * HW);
        return;
    }

    // ---- stage precomposed weights for this og into LDS (3 float4 per thread) ----
    const float* wgp = wcomp + WG_OFF + og * (CIN * 48);
#pragma unroll
    for (int k = 0; k < 3; ++k) {
        int e = (tid + k * 256) * 4;
        *(float4*)&swf[e] = *(const float4*)&wgp[e];
    }
    if (tid < 16) {
        int o = og * 16 + tid;
        sbd[tid] = wcomp[BD_OFF + o];
        sbb[tid] = wcomp[BB_OFF + o];
        snA[tid] = -expf(A[o]);
        sbi[tid] = b_in[o];
    }
    __syncthreads();

    // ---- main GEMV loop (K=64), packed fp32 ----
    v2f ai[16][2], ad[16][2], ab[16][2];
#pragma unroll
    for (int j = 0; j < 16; ++j)
#pragma unroll
        for (int k = 0; k < 2; ++k) {
            ai[j][k] = (v2f){0.f, 0.f};
            ad[j][k] = (v2f){0.f, 0.f};
            ab[j][k] = (v2f){0.f, 0.f};
        }

    const float* xb = x + b * (CIN * HW) + p0;
    for (int c = 0; c < CIN; ++c) {
        float4 xv = *(const float4*)(xb + c * HW);
        v2f xlo = (v2f){xv.x, xv.y};
        v2f xhi = (v2f){xv.z, xv.w};
        const float* w = &swf[c * 48];
#pragma unroll
        for (int j = 0; j < 16; ++j) {
            v2f wi = (v2f){w[j],      w[j]};
            v2f wd = (v2f){w[16 + j], w[16 + j]};
            v2f wb = (v2f){w[32 + j], w[32 + j]};
            ai[j][0] = __builtin_elementwise_fma(wi, xlo, ai[j][0]);
            ai[j][1] = __builtin_elementwise_fma(wi, xhi, ai[j][1]);
            ad[j][0] = __builtin_elementwise_fma(wd, xlo, ad[j][0]);
            ad[j][1] = __builtin_elementwise_fma(wd, xhi, ad[j][1]);
            ab[j][0] = __builtin_elementwise_fma(wb, xlo, ab[j][0]);
            ab[j][1] = __builtin_elementwise_fma(wb, xhi, ab[j][1]);
        }
    }

    const float lam = lam_p[0], alpha = alpha_p[0];
    int base = b * (HID * HW) + p0;
#pragma unroll
    for (int j = 0; j < 16; ++j) {
        int o = og * 16 + j;
        float bi = sbi[j], bd = sbd[j], bb2 = sbb[j], nA = snA[j];
        float adv[4] = {ad[j][0].x, ad[j][0].y, ad[j][1].x, ad[j][1].y};
        float aiv[4] = {ai[j][0].x, ai[j][0].y, ai[j][1].x, ai[j][1].y};
        float abv[4] = {ab[j][0].x, ab[j][0].y, ab[j][1].x, ab[j][1].y};
        float Ao[4], bo[4];
#pragma unroll
        for (int k = 0; k < 4; ++k) {
            float dv = adv[k] + bd + lam * pus[k];
            float d  = fmaxf(dv, 0.f) + log1pf(expf(-fabsf(dv)));   // softplus
            Ao[k] = expf(d * nA);
            float feat = aiv[k] + bi;
            float Bk = (abv[k] + bb2) * (1.f + alpha * pus[k]);
            bo[k] = d * Bk * feat;
        }
        *(h4*)(Abar + base + o * HW) =
            (h4){(_Float16)Ao[0], (_Float16)Ao[1], (_Float16)Ao[2], (_Float16)Ao[3]};
        *(h4*)(bbuf + base + o * HW) =
            (h4){(_Float16)bo[0], (_Float16)bo[1], (_Float16)bo[2], (_Float16)bo[3]};
    }
}

// =================== L2: vertical scan, thread-per-column (round-6 verbatim) ===================
__global__ __launch_bounds__(256) void vscan_kernel(const _Float16* __restrict__ Abar,
                                                    const _Float16* __restrict__ bbuf,
                                                    _Float16* __restrict__ vsum,
                                                    const float* __restrict__ gamma_p) {
    if (gamma_p[0] == 0.f) return;
    int idx = blockIdx.x * 256 + threadIdx.x;              // [0,131072): (plane)*WD + col
    int base = (idx >> 7) * HW + (idx & 127);
    float P = 1.f, s = 0.f;
    for (int i = 0; i < HD; ++i) {
        int off = base + i * WD;
        float a  = (float)Abar[off];
        float bv = (float)bbuf[off];
        P *= a;
        s += bv / fmaxf(P, 1e-8f);
        vsum[off] = (_Float16)(P * s);
    }
}

// ====== L3: h-scan + vsum add -> LDS, then out conv + residual (round-6 verbatim) ======
__global__ __launch_bounds__(256, 2) void hconv_kernel(const _Float16* __restrict__ Abar,
                                                       const _Float16* __restrict__ bbuf,
                                                       const _Float16* __restrict__ vsum,
                                                       const float* __restrict__ x,
                                                       const float* __restrict__ W_out,
                                                       const float* __restrict__ b_out,
                                                       const float* __restrict__ gamma_p,
                                                       float* __restrict__ out0) {
    float g = gamma_p[0];
    if (g == 0.f) return;
    __shared__ float slds[HID][WD];                        // 64 KB: sum[c][px] for this row
    int row = blockIdx.x, b = blockIdx.y;
    int t = threadIdx.x, lane = t & 63, wv = t >> 6;
    const _Float16* Ab = Abar + (size_t)b * HID * HW + row * WD;
    const _Float16* Bb = bbuf + (size_t)b * HID * HW + row * WD;
    const _Float16* Vb = vsum + (size_t)b * HID * HW + row * WD;
    for (int it = 0; it < 32; ++it) {
        int c = wv * 32 + it;
        int coff = c * HW + lane * 2;
        h2 a2 = *(const h2*)(Ab + coff);
        h2 b2 = *(const h2*)(Bb + coff);
        float pa = (float)a2.x, pb0 = (float)a2.y;
        float bx0 = (float)b2.x, bx1 = (float)b2.y;
        float pb = pa * pb0;
        float Lp = pb;
#pragma unroll
        for (int off = 1; off < 64; off <<= 1) {
            float tt = __shfl_up(Lp, off, 64);
            if (lane >= off) Lp *= tt;
        }
        float ep = __shfl_up(Lp, 1, 64);
        if (lane == 0) ep = 1.f;
        float P0 = ep * pa, P1 = ep * pb;
        float q0 = bx0 / fmaxf(P0, 1e-8f);
        float q1 = bx1 / fmaxf(P1, 1e-8f);
        float s0 = q0, s1 = q0 + q1;
        float Ls = s1;
#pragma unroll
        for (int off = 1; off < 64; off <<= 1) {
            float tt = __shfl_up(Ls, off, 64);
            if (lane >= off) Ls += tt;
        }
        float es = __shfl_up(Ls, 1, 64);
        if (lane == 0) es = 0.f;
        float h0 = P0 * (es + s0), h1 = P1 * (es + s1);
        h2 v2 = *(const h2*)(Vb + coff);
        *(float2*)(&slds[c][lane * 2]) = make_float2(h0 + (float)v2.x, h1 + (float)v2.y);
    }
    __syncthreads();
    int wvu = __builtin_amdgcn_readfirstlane(wv);
    const float* wrow = W_out + wvu * 16 * HID;            // uniform base -> s_loads
    v2f acc[16];
#pragma unroll
    for (int j = 0; j < 16; ++j) acc[j] = (v2f){0.f, 0.f};
    for (int c = 0; c < HID; ++c) {
        v2f sv = *(const v2f*)(&slds[c][lane * 2]);
#pragma unroll
        for (int j = 0; j < 16; ++j) {
            float wj = wrow[j * HID + c];                  // wave-uniform scalar load
            v2f w2 = (v2f){wj, wj};
            acc[j] = __builtin_elementwise_fma(w2, sv, acc[j]);
        }
    }
#pragma unroll
    for (int j = 0; j < 16; ++j) {
        int o = wvu * 16 + j;
        float bo = b_out[o];
        int oi = b * (CIN * HW) + o * HW + row * WD + lane * 2;
        float2 xv = *(const float2*)(x + oi);
        float2 o2;
        o2.x = xv.x + g * (acc[j].x + bo);
        o2.y = xv.y + g * (acc[j].y + bo);
        *(float2*)(out0 + oi) = o2;
    }
}

extern "C" void kernel_launch(void* const* d_in, const int* in_sizes, int n_in,
                              void* d_out, int out_size, void* d_ws, size_t ws_size,
                              hipStream_t stream) {
    const float* x       = (const float*)d_in[0];
    const float* prior   = (const float*)d_in[1];
    const float* W_in    = (const float*)d_in[2];
    const float* b_in    = (const float*)d_in[3];
    const float* W_out   = (const float*)d_in[4];
    const float* b_out   = (const float*)d_in[5];
    const float* W_delta = (const float*)d_in[6];
    const float* b_delta = (const float*)d_in[7];
    const float* W_B     = (const float*)d_in[8];
    const float* b_B     = (const float*)d_in[9];
    const float* lam     = (const float*)d_in[10];
    const float* alpha   = (const float*)d_in[11];
    const float* A       = (const float*)d_in[12];
    const float* gamma   = (const float*)d_in[13];

    float* out0 = (float*)d_out;                       // [8,64,128,128]
    float* out1 = (float*)d_out + NB * CIN * HW;       // prior_up [8,1,128,128]

    const size_t FIELD = (size_t)NB * HID * HW;        // 16,777,216 elements
    _Float16* Abar = (_Float16*)d_ws;                  // three fp16 fields: 3 * 33.5 MB
    _Float16* bbuf = Abar + FIELD;
    _Float16* vsum = bbuf + FIELD;
    float* wcomp   = (float*)(vsum + FIELD);           // 24,832 floats

    // L0: one-shot weight compose (dedups 128x redundant per-block compose)
    wprep_kernel<<<dim3(33), dim3(256), 0, stream>>>(
        W_in, b_in, W_delta, b_delta, W_B, b_B, wcomp);
    // L1: fused upsample + gate (also handles gamma==0 copy)
    gate_kernel<<<dim3(16, 8, NB), dim3(256), 0, stream>>>(
        x, prior, b_in, wcomp, lam, alpha, A, gamma, Abar, bbuf, out0, out1);
    // L2: vertical scan -> vsum (fp16)
    vscan_kernel<<<dim3(512), dim3(256), 0, stream>>>(Abar, bbuf, vsum, gamma);
    // L3: h-scan + vsum add + output conv + residual
    hconv_kernel<<<dim3(HD, NB), dim3(256), 0, stream>>>(
        Abar, bbuf, vsum, x, W_out, b_out, gamma, out0);
}

// Round 10
// 108.365 us; speedup vs baseline: 1.0753x; 1.0753x over previous
//
#include <hip/hip_runtime.h>
#include <math.h>

#define HID 128
#define CIN 64
#define NB 8
#define HD 128
#define WD 128
#define HW (HD*WD)   // 16384

typedef float v2f __attribute__((ext_vector_type(2)));
typedef _Float16 h2 __attribute__((ext_vector_type(2)));
typedef _Float16 h4 __attribute__((ext_vector_type(4)));

// ======= L1: fused gate (round-6 winner, unchanged) =======
__global__ __launch_bounds__(256, 2) void gate_kernel(const float* __restrict__ x,
                                                      const float* __restrict__ prior,
                                                      const float* __restrict__ W_in,
                                                      const float* __restrict__ b_in,
                                                      const float* __restrict__ W_delta,
                                                      const float* __restrict__ b_delta,
                                                      const float* __restrict__ W_B,
                                                      const float* __restrict__ b_B,
                                                      const float* __restrict__ lam_p,
                                                      const float* __restrict__ alpha_p,
                                                      const float* __restrict__ A,
                                                      const float* __restrict__ gamma_p,
                                                      _Float16* __restrict__ Abar,
                                                      _Float16* __restrict__ bbuf,
                                                      float* __restrict__ out0,
                                                      float* __restrict__ out1) {
    __shared__ float sw[CIN][48];                          // {W_in | Wd' | Wb'} x 16 outs, 12 KB
    __shared__ float sbd[16], sbb[16], snA[16], sbi[16];
    const int bx = blockIdx.x, og = blockIdx.y, b = blockIdx.z;
    const int tid = threadIdx.x;
    const int p0 = bx * 1024 + tid * 4;
    const float g = gamma_p[0];

    // ---- inline prior upsample for this thread's 4 px (same row) ----
    const float scale = 63.0f / 127.0f;
    int i = p0 >> 7;
    float ys = i * scale;
    int y0 = (int)floorf(ys); int y1 = min(y0 + 1, 63);
    float wy = ys - (float)y0;
    const float* pp = prior + b * 4096;
    int col0 = p0 & 127;
    float pus[4];
#pragma unroll
    for (int k = 0; k < 4; ++k) {
        float xs = (col0 + k) * scale;
        int x0 = (int)floorf(xs); int x1 = min(x0 + 1, 63);
        float wx = xs - (float)x0;
        float v00 = pp[y0 * 64 + x0], v01 = pp[y0 * 64 + x1];
        float v10 = pp[y1 * 64 + x0], v11 = pp[y1 * 64 + x1];
        float r0 = v00 * (1.f - wy) + v10 * wy;
        float r1 = v01 * (1.f - wy) + v11 * wy;
        float v = r0 * (1.f - wx) + r1 * wx;
        pus[k] = fminf(fmaxf(v, -1.f), 1.f);
    }
    if (og == 0)
        *(float4*)(out1 + b * HW + p0) = make_float4(pus[0], pus[1], pus[2], pus[3]);

    // ---- gamma==0: out0 = x (this block's 8-channel slab), done ----
    if (g == 0.f) {
        const float* xs0 = x + b * (CIN * HW) + (og * 8) * HW + p0;
        float* o0 = out0 + b * (CIN * HW) + (og * 8) * HW + p0;
#pragma unroll
        for (int ch = 0; ch < 8; ++ch)
            *(float4*)(o0 + ch * HW) = *(const float4*)(xs0 + ch * HW);
        return;
    }

    // ---- compose weights for this block's 16 out-channels into LDS ----
#pragma unroll
    for (int k = 0; k < 4; ++k) {
        int e = tid + k * 256;                             // [0,1024): c = e>>4, j = e&15
        int c = e >> 4, j = e & 15;
        int o = og * 16 + j;
        float wd = 0.f, wb = 0.f;
        for (int h = 0; h < HID; ++h) {
            float wi = W_in[h * CIN + c];
            wd = fmaf(W_delta[o * HID + h], wi, wd);
            wb = fmaf(W_B[o * HID + h], wi, wb);
        }
        sw[c][j]      = W_in[o * CIN + c];
        sw[c][16 + j] = wd;
        sw[c][32 + j] = wb;
    }
    if (tid < 16) {
        int o = og * 16 + tid;
        float sd = b_delta[o], sb = b_B[o];
        for (int h = 0; h < HID; ++h) {
            float bi = b_in[h];
            sd = fmaf(W_delta[o * HID + h], bi, sd);
            sb = fmaf(W_B[o * HID + h], bi, sb);
        }
        sbd[tid] = sd; sbb[tid] = sb;
        snA[tid] = -expf(A[o]); sbi[tid] = b_in[o];
    }
    __syncthreads();

    // ---- main GEMV loop (K=64), packed fp32 ----
    v2f ai[16][2], ad[16][2], ab[16][2];
#pragma unroll
    for (int j = 0; j < 16; ++j)
#pragma unroll
        for (int k = 0; k < 2; ++k) {
            ai[j][k] = (v2f){0.f, 0.f};
            ad[j][k] = (v2f){0.f, 0.f};
            ab[j][k] = (v2f){0.f, 0.f};
        }

    const float* xb = x + b * (CIN * HW) + p0;
    for (int c = 0; c < CIN; ++c) {
        float4 xv = *(const float4*)(xb + c * HW);
        v2f xlo = (v2f){xv.x, xv.y};
        v2f xhi = (v2f){xv.z, xv.w};
        const float* w = sw[c];
#pragma unroll
        for (int j = 0; j < 16; ++j) {
            v2f wi = (v2f){w[j],      w[j]};
            v2f wd = (v2f){w[16 + j], w[16 + j]};
            v2f wb = (v2f){w[32 + j], w[32 + j]};
            ai[j][0] = __builtin_elementwise_fma(wi, xlo, ai[j][0]);
            ai[j][1] = __builtin_elementwise_fma(wi, xhi, ai[j][1]);
            ad[j][0] = __builtin_elementwise_fma(wd, xlo, ad[j][0]);
            ad[j][1] = __builtin_elementwise_fma(wd, xhi, ad[j][1]);
            ab[j][0] = __builtin_elementwise_fma(wb, xlo, ab[j][0]);
            ab[j][1] = __builtin_elementwise_fma(wb, xhi, ab[j][1]);
        }
    }

    const float lam = lam_p[0], alpha = alpha_p[0];
    int base = b * (HID * HW) + p0;
#pragma unroll
    for (int j = 0; j < 16; ++j) {
        int o = og * 16 + j;
        float bi = sbi[j], bd = sbd[j], bb2 = sbb[j], nA = snA[j];
        float adv[4] = {ad[j][0].x, ad[j][0].y, ad[j][1].x, ad[j][1].y};
        float aiv[4] = {ai[j][0].x, ai[j][0].y, ai[j][1].x, ai[j][1].y};
        float abv[4] = {ab[j][0].x, ab[j][0].y, ab[j][1].x, ab[j][1].y};
        float Ao[4], bo[4];
#pragma unroll
        for (int k = 0; k < 4; ++k) {
            float dv = adv[k] + bd + lam * pus[k];
            float d  = fmaxf(dv, 0.f) + log1pf(expf(-fabsf(dv)));   // softplus
            Ao[k] = expf(d * nA);
            float feat = aiv[k] + bi;
            float Bk = (abv[k] + bb2) * (1.f + alpha * pus[k]);
            bo[k] = d * Bk * feat;
        }
        *(h4*)(Abar + base + o * HW) =
            (h4){(_Float16)Ao[0], (_Float16)Ao[1], (_Float16)Ao[2], (_Float16)Ao[3]};
        *(h4*)(bbuf + base + o * HW) =
            (h4){(_Float16)bo[0], (_Float16)bo[1], (_Float16)bo[2], (_Float16)bo[3]};
    }
}

// =================== L2: vertical scan, thread-per-column (round-6 verbatim) ===================
__global__ __launch_bounds__(256) void vscan_kernel(const _Float16* __restrict__ Abar,
                                                    const _Float16* __restrict__ bbuf,
                                                    _Float16* __restrict__ vsum,
                                                    const float* __restrict__ gamma_p) {
    if (gamma_p[0] == 0.f) return;
    int idx = blockIdx.x * 256 + threadIdx.x;              // [0,131072): (plane)*WD + col
    int base = (idx >> 7) * HW + (idx & 127);
    float P = 1.f, s = 0.f;
    for (int i = 0; i < HD; ++i) {
        int off = base + i * WD;
        float a  = (float)Abar[off];
        float bv = (float)bbuf[off];
        P *= a;
        s += bv / fmaxf(P, 1e-8f);
        vsum[off] = (_Float16)(P * s);
    }
}

// ====== L3: h-scan + vsum add -> fp16 LDS (32 KB, 4 blocks/CU), then out conv + residual ======
__global__ __launch_bounds__(256, 4) void hconv_kernel(const _Float16* __restrict__ Abar,
                                                       const _Float16* __restrict__ bbuf,
                                                       const _Float16* __restrict__ vsum,
                                                       const float* __restrict__ x,
                                                       const float* __restrict__ W_out,
                                                       const float* __restrict__ b_out,
                                                       const float* __restrict__ gamma_p,
                                                       float* __restrict__ out0) {
    float g = gamma_p[0];
    if (g == 0.f) return;
    __shared__ _Float16 slds[HID][WD];                     // 32 KB: sum[c][px], fp16 (validated)
    int row = blockIdx.x, b = blockIdx.y;
    int t = threadIdx.x, lane = t & 63, wv = t >> 6;
    const _Float16* Ab = Abar + (size_t)b * HID * HW + row * WD;
    const _Float16* Bb = bbuf + (size_t)b * HID * HW + row * WD;
    const _Float16* Vb = vsum + (size_t)b * HID * HW + row * WD;
    for (int it = 0; it < 32; ++it) {
        int c = wv * 32 + it;
        int coff = c * HW + lane * 2;
        h2 a2 = *(const h2*)(Ab + coff);
        h2 b2 = *(const h2*)(Bb + coff);
        float pa = (float)a2.x, pb0 = (float)a2.y;
        float bx0 = (float)b2.x, bx1 = (float)b2.y;
        float pb = pa * pb0;
        float Lp = pb;
#pragma unroll
        for (int off = 1; off < 64; off <<= 1) {
            float tt = __shfl_up(Lp, off, 64);
            if (lane >= off) Lp *= tt;
        }
        float ep = __shfl_up(Lp, 1, 64);
        if (lane == 0) ep = 1.f;
        float P0 = ep * pa, P1 = ep * pb;
        float q0 = bx0 / fmaxf(P0, 1e-8f);
        float q1 = bx1 / fmaxf(P1, 1e-8f);
        float s0 = q0, s1 = q0 + q1;
        float Ls = s1;
#pragma unroll
        for (int off = 1; off < 64; off <<= 1) {
            float tt = __shfl_up(Ls, off, 64);
            if (lane >= off) Ls += tt;
        }
        float es = __shfl_up(Ls, 1, 64);
        if (lane == 0) es = 0.f;
        float h0 = P0 * (es + s0), h1 = P1 * (es + s1);
        h2 v2 = *(const h2*)(Vb + coff);
        *(h2*)(&slds[c][lane * 2]) = (h2){(_Float16)(h0 + (float)v2.x),
                                          (_Float16)(h1 + (float)v2.y)};
    }
    __syncthreads();
    int wvu = __builtin_amdgcn_readfirstlane(wv);
    const float* wrow = W_out + wvu * 16 * HID;            // uniform base -> s_loads
    v2f acc[16];
#pragma unroll
    for (int j = 0; j < 16; ++j) acc[j] = (v2f){0.f, 0.f};
    for (int c = 0; c < HID; ++c) {
        h2 sv16 = *(const h2*)(&slds[c][lane * 2]);
        v2f sv = (v2f){(float)sv16.x, (float)sv16.y};
#pragma unroll
        for (int j = 0; j < 16; ++j) {
            float wj = wrow[j * HID + c];                  // wave-uniform scalar load
            v2f w2 = (v2f){wj, wj};
            acc[j] = __builtin_elementwise_fma(w2, sv, acc[j]);
        }
    }
#pragma unroll
    for (int j = 0; j < 16; ++j) {
        int o = wvu * 16 + j;
        float bo = b_out[o];
        int oi = b * (CIN * HW) + o * HW + row * WD + lane * 2;
        float2 xv = *(const float2*)(x + oi);
        float2 o2;
        o2.x = xv.x + g * (acc[j].x + bo);
        o2.y = xv.y + g * (acc[j].y + bo);
        *(float2*)(out0 + oi) = o2;
    }
}

extern "C" void kernel_launch(void* const* d_in, const int* in_sizes, int n_in,
                              void* d_out, int out_size, void* d_ws, size_t ws_size,
                              hipStream_t stream) {
    const float* x       = (const float*)d_in[0];
    const float* prior   = (const float*)d_in[1];
    const float* W_in    = (const float*)d_in[2];
    const float* b_in    = (const float*)d_in[3];
    const float* W_out   = (const float*)d_in[4];
    const float* b_out   = (const float*)d_in[5];
    const float* W_delta = (const float*)d_in[6];
    const float* b_delta = (const float*)d_in[7];
    const float* W_B     = (const float*)d_in[8];
    const float* b_B     = (const float*)d_in[9];
    const float* lam     = (const float*)d_in[10];
    const float* alpha   = (const float*)d_in[11];
    const float* A       = (const float*)d_in[12];
    const float* gamma   = (const float*)d_in[13];

    float* out0 = (float*)d_out;                       // [8,64,128,128]
    float* out1 = (float*)d_out + NB * CIN * HW;       // prior_up [8,1,128,128]

    const size_t FIELD = (size_t)NB * HID * HW;        // 16,777,216 elements
    _Float16* Abar = (_Float16*)d_ws;                  // three fp16 fields: 3 * 33.5 MB
    _Float16* bbuf = Abar + FIELD;
    _Float16* vsum = bbuf + FIELD;

    // L1: fused upsample + weight compose + gate (also handles gamma==0 copy)
    gate_kernel<<<dim3(16, 8, NB), dim3(256), 0, stream>>>(
        x, prior, W_in, b_in, W_delta, b_delta, W_B, b_B,
        lam, alpha, A, gamma, Abar, bbuf, out0, out1);
    // L2: vertical scan -> vsum (fp16)
    vscan_kernel<<<dim3(512), dim3(256), 0, stream>>>(Abar, bbuf, vsum, gamma);
    // L3: h-scan + vsum add + output conv + residual (fp16 LDS, 4 blocks/CU)
    hconv_kernel<<<dim3(HD, NB), dim3(256), 0, stream>>>(
        Abar, bbuf, vsum, x, W_out, b_out, gamma, out0);
}